// Round 6
// baseline (1787.987 us; speedup 1.0000x reference)
//
#include <hip/hip_runtime.h>
#include <stdint.h>
#include <stddef.h>

#define MSTEPS 128
#define NB 1024
#define ED 512
#define GD 1536
#define VS 32000

// GRU decomposition: 64 row-blocks x 16 rows, 4 col-WGs x 128 cols.
// 256 WGs x 512 threads (8 waves). W_hh in VGPRs (192/lane). All
// cross-WG exchange via agent-scope (L3) atomics -- r3-proven protocol.
#define RB 16
#define CB 128
#define NGR 64   // row-block groups
#define NSH 4    // sharers (col-WGs) per group
#define GIST 392 // gi LDS row stride (elems): 3*128 data + 8 pad
#define STST 136 // stl LDS row stride (elems): 128 data + 8 pad

typedef __attribute__((ext_vector_type(4))) float f32x4;
typedef __attribute__((ext_vector_type(8))) short s16x8;
typedef __attribute__((ext_vector_type(4))) short s16x4;
typedef __attribute__((ext_vector_type(8))) unsigned short u16x8;

__device__ __forceinline__ unsigned short f2bf(float f) {
  unsigned x = __builtin_bit_cast(unsigned, f);
  x = x + 0x7fffu + ((x >> 16) & 1u);
  return (unsigned short)(x >> 16);
}
__device__ __forceinline__ float bf2f(unsigned short u) {
  return __builtin_bit_cast(float, ((unsigned)u) << 16);
}
__device__ __forceinline__ float sigm(float x) { return 1.0f / (1.0f + __expf(-x)); }
__device__ __forceinline__ float tanh_(float x) {
  x = fminf(15.0f, fmaxf(-15.0f, x));
  float e = __expf(-2.0f * x);
  return (1.0f - e) / (1.0f + e);
}

// ---------------- Kernel 1: projected vocab table (r2-proven) ----------------
__global__ __launch_bounds__(256) void table_kernel(
    const float* __restrict__ emb, const float* __restrict__ Wih,
    const float* __restrict__ bih, unsigned short* __restrict__ tab)
{
  __shared__ short Al[128 * 64];
  __shared__ short Bl[128 * 64];
  const int tid = threadIdx.x;
  const int lane = tid & 63;
  const int l15 = lane & 15, l4 = lane >> 4;
  const int wv = tid >> 6;
  const int rh = wv & 1, ch = wv >> 1;
  const int row0 = blockIdx.x * 128;
  const int col0 = blockIdx.y * 128;

  f32x4 acc[4][4];
  #pragma unroll
  for (int m = 0; m < 4; m++)
    #pragma unroll
    for (int n = 0; n < 4; n++) acc[m][n] = (f32x4){0.f, 0.f, 0.f, 0.f};

  for (int ko = 0; ko < ED; ko += 64) {
    #pragma unroll
    for (int i = 0; i < 8; i++) {
      int idx = tid + i * 256;
      int r = idx >> 4, c4 = idx & 15;
      int ba = (r * 128 + c4 * 8) ^ ((r & 7) << 4);
      f32x4 va = *(const f32x4*)(emb + (size_t)(row0 + r) * ED + ko + c4 * 4);
      s16x4 pa;
      pa[0] = (short)f2bf(va[0]); pa[1] = (short)f2bf(va[1]);
      pa[2] = (short)f2bf(va[2]); pa[3] = (short)f2bf(va[3]);
      *(s16x4*)((char*)Al + ba) = pa;
      f32x4 vb = *(const f32x4*)(Wih + (size_t)(col0 + r) * ED + ko + c4 * 4);
      s16x4 pb;
      pb[0] = (short)f2bf(vb[0]); pb[1] = (short)f2bf(vb[1]);
      pb[2] = (short)f2bf(vb[2]); pb[3] = (short)f2bf(vb[3]);
      *(s16x4*)((char*)Bl + ba) = pb;
    }
    __syncthreads();
    #pragma unroll
    for (int kk = 0; kk < 2; kk++) {
      s16x8 af[4], bfv[4];
      #pragma unroll
      for (int m = 0; m < 4; m++) {
        int row = rh * 64 + m * 16 + l15;
        int ad = (row * 128 + kk * 64 + l4 * 16) ^ ((row & 7) << 4);
        af[m] = *(const s16x8*)((char*)Al + ad);
      }
      #pragma unroll
      for (int n = 0; n < 4; n++) {
        int col = ch * 64 + n * 16 + l15;
        int ad = (col * 128 + kk * 64 + l4 * 16) ^ ((col & 7) << 4);
        bfv[n] = *(const s16x8*)((char*)Bl + ad);
      }
      #pragma unroll
      for (int m = 0; m < 4; m++)
        #pragma unroll
        for (int n = 0; n < 4; n++)
          acc[m][n] = __builtin_amdgcn_mfma_f32_16x16x32_bf16(af[m], bfv[n], acc[m][n], 0, 0, 0);
    }
    __syncthreads();
  }

  float bias_n[4];
  #pragma unroll
  for (int n = 0; n < 4; n++) bias_n[n] = bih[col0 + ch * 64 + n * 16 + l15];
  #pragma unroll
  for (int m = 0; m < 4; m++)
    #pragma unroll
    for (int n = 0; n < 4; n++) {
      int colg = col0 + ch * 64 + n * 16 + l15;
      #pragma unroll
      for (int j = 0; j < 4; j++) {
        int rowg = row0 + rh * 64 + m * 16 + l4 * 4 + j;
        tab[(size_t)rowg * GD + colg] = f2bf(acc[m][n][j] + bias_n[n]);
      }
    }
}

// ---------------- Kernel 2: persistent GRU scan ----------------
__global__ __launch_bounds__(512, 2) void gru_kernel(
    const int* __restrict__ utt, const float* __restrict__ Whh,
    const float* __restrict__ bhh, const unsigned short* __restrict__ tab,
    unsigned short* st, unsigned* cnt, const int* __restrict__ termp,
    float* __restrict__ out)
{
  __shared__ __align__(16) char sls[RB * 1024];            // state tile 16KB
  __shared__ __align__(16) unsigned short gil[RB * GIST];  // ~12.3KB
  __shared__ __align__(16) unsigned short stl[RB * STST];  // ~4.3KB
  __shared__ int abl;

  const int tid = threadIdx.x;
  const int lane = tid & 63;
  const int l15 = lane & 15, l4 = lane >> 4;
  const int wv = tid >> 6;                 // wave 0..7
  const int bid = blockIdx.x;
  const int rblk = bid & (NGR - 1);        // 0..63
  const int cblk = bid >> 6;               // 0..3
  const int r0 = rblk * RB, c0 = cblk * CB;
  const int wc = wv * 16 + l15;            // col within WG tile, 0..127
  const int termid = termp[0];

  unsigned* cnt_r = cnt + rblk * 32;       // 128B apart per group
  int* abort_g = (int*)(cnt + 2048);

  // ---- W_hh fragments -> VGPRs (held for all 128 steps) ----
  s16x8 bfr[3][16];
  #pragma unroll
  for (int g = 0; g < 3; g++)
    #pragma unroll
    for (int kk = 0; kk < 16; kk++) {
      const float* src = Whh + (size_t)(g * ED + c0 + wc) * ED + kk * 32 + l4 * 8;
      f32x4 v0 = *(const f32x4*)(src);
      f32x4 v1 = *(const f32x4*)(src + 4);
      s16x8 p;
      p[0] = (short)f2bf(v0[0]); p[1] = (short)f2bf(v0[1]);
      p[2] = (short)f2bf(v0[2]); p[3] = (short)f2bf(v0[3]);
      p[4] = (short)f2bf(v1[0]); p[5] = (short)f2bf(v1[1]);
      p[6] = (short)f2bf(v1[2]); p[7] = (short)f2bf(v1[3]);
      bfr[g][kk] = p;
    }

  float bh[3];
  #pragma unroll
  for (int g = 0; g < 3; g++) bh[g] = bhh[g * ED + c0 + wc];

  float ms[4] = {0.f, 0.f, 0.f, 0.f};     // master state: rows l4*4+j, col wc
  unsigned am = 0xFu;                      // alive bits, 4 owned rows

  // gather units: 768 x 16B per step; thread handles u0 (+u1 if tid<256)
  const int u0 = tid, u1 = 512 + tid;
  const int r0u0 = u0 / 48, sg0 = u0 % 48;
  const int r0u1 = u1 / 48, sg1 = u1 % 48;

  // prefetch step-0 gather
  u16x8 pgA, pgB;
  {
    int tokA = utt[r0 + r0u0];
    pgA = *(const u16x8*)(tab + (size_t)tokA * GD + (sg0 >> 4) * ED + c0 + (sg0 & 15) * 8);
    if (tid < 256) {
      int tokB = utt[r0 + r0u1];
      pgB = *(const u16x8*)(tab + (size_t)tokB * GD + (sg1 >> 4) * ED + c0 + (sg1 & 15) * 8);
    }
  }

  for (int s = 0; s < MSTEPS; s++) {
    const unsigned short* rdb = st + (size_t)((s + 3) & 3) * NB * ED;
    unsigned short* wrb = st + (size_t)(s & 3) * NB * ED;

    // 1) coalesced agent-scope state load (16KB/WG) -- skipped at s=0 (h=0)
    unsigned long long sld[4];
    if (s > 0) {
      const unsigned long long* sb = (const unsigned long long*)(rdb + (size_t)r0 * ED);
      #pragma unroll
      for (int k = 0; k < 4; k++)
        sld[k] = __hip_atomic_load(sb + k * 512 + tid, __ATOMIC_RELAXED, __HIP_MEMORY_SCOPE_AGENT);
    }

    // 2) park prefetched gi into LDS; load this step's alive tokens
    *(u16x8*)(gil + r0u0 * GIST + (sg0 >> 4) * 128 + (sg0 & 15) * 8) = pgA;
    if (tid < 256)
      *(u16x8*)(gil + r0u1 * GIST + (sg1 >> 4) * 128 + (sg1 & 15) * 8) = pgB;
    int tk[4];
    #pragma unroll
    for (int j = 0; j < 4; j++) tk[j] = utt[s * NB + r0 + l4 * 4 + j];

    // 3) state regs -> LDS, XOR-swizzled rows
    if (s > 0) {
      #pragma unroll
      for (int k = 0; k < 4; k++) {
        int i = k * 512 + tid;
        int row = i >> 7;
        int o = row * 1024 + (i & 127) * 8;
        *(unsigned long long*)(sls + (o ^ ((row & 7) << 4))) = sld[k];
      }
    }
    __syncthreads();

    // 4) prefetch next step's gather (hidden under MFMA)
    if (s + 1 < MSTEPS) {
      int tokA = utt[(s + 1) * NB + r0 + r0u0];
      pgA = *(const u16x8*)(tab + (size_t)tokA * GD + (sg0 >> 4) * ED + c0 + (sg0 & 15) * 8);
      if (tid < 256) {
        int tokB = utt[(s + 1) * NB + r0 + r0u1];
        pgB = *(const u16x8*)(tab + (size_t)tokB * GD + (sg1 >> 4) * ED + c0 + (sg1 & 15) * 8);
      }
    }

    // 5) gh = state @ Whh^T  (A from LDS, B from registers); s=0: gh=0
    f32x4 acc[3];
    #pragma unroll
    for (int g = 0; g < 3; g++) acc[g] = (f32x4){0.f, 0.f, 0.f, 0.f};
    if (s > 0) {
      #pragma unroll
      for (int kk = 0; kk < 16; kk++) {
        int ad = (l15 * 1024 + kk * 64 + l4 * 16) ^ ((l15 & 7) << 4);
        s16x8 av = *(const s16x8*)(sls + ad);
        #pragma unroll
        for (int g = 0; g < 3; g++)
          acc[g] = __builtin_amdgcn_mfma_f32_16x16x32_bf16(av, bfr[g][kk], acc[g], 0, 0, 0);
      }
    }

    // 6) epilogue: gates + blend (f32 master state in regs)
    #pragma unroll
    for (int j = 0; j < 4; j++) {
      int row = l4 * 4 + j;
      float hr = acc[0][j] + bh[0];
      float hz = acc[1][j] + bh[1];
      float hn = acc[2][j] + bh[2];
      float ir = bf2f(gil[row * GIST + 0 * 128 + wc]);
      float iz = bf2f(gil[row * GIST + 1 * 128 + wc]);
      float in_ = bf2f(gil[row * GIST + 2 * 128 + wc]);
      float r = sigm(ir + hr);
      float z = sigm(iz + hz);
      float nn = tanh_(in_ + r * hn);
      float old = ms[j];
      float nu = (1.0f - z) * nn + z * old;
      float res = ((am >> j) & 1u) ? nu : old;
      ms[j] = res;
      stl[row * STST + wc] = f2bf(res);
      if (tk[j] == termid) am &= ~(1u << j);
    }
    __syncthreads();

    // 7) cooperative agent-scope store of new state slice (4KB/WG)
    {
      int srow = tid >> 5, sseg = tid & 31;
      unsigned long long v = *(const unsigned long long*)(stl + srow * STST + sseg * 4);
      unsigned long long* dst =
          (unsigned long long*)(wrb + (size_t)(r0 + srow) * ED + c0 + sseg * 4);
      __hip_atomic_store(dst, v, __ATOMIC_RELAXED, __HIP_MEMORY_SCOPE_AGENT);
    }

    // 8) per-row-block barrier (4 WGs), timeout -> abort (no hang)
    asm volatile("s_waitcnt vmcnt(0)" ::: "memory");
    __syncthreads();
    if (tid == 0) {
      __hip_atomic_fetch_add(cnt_r, 1u, __ATOMIC_RELEASE, __HIP_MEMORY_SCOPE_AGENT);
      unsigned target = (unsigned)NSH * (unsigned)(s + 1);
      unsigned long long t0 = __builtin_amdgcn_s_memrealtime();
      int ab = 0, pc = 0;
      while (__hip_atomic_load(cnt_r, __ATOMIC_RELAXED, __HIP_MEMORY_SCOPE_AGENT) < target) {
        if (((++pc) & 63) == 0) {
          if (__hip_atomic_load(abort_g, __ATOMIC_RELAXED, __HIP_MEMORY_SCOPE_AGENT)) { ab = 1; break; }
          if (__builtin_amdgcn_s_memrealtime() - t0 > 20000000ULL) {
            __hip_atomic_store(abort_g, 1, __ATOMIC_RELAXED, __HIP_MEMORY_SCOPE_AGENT);
            ab = 1; break;
          }
        }
      }
      abl = ab;
    }
    __syncthreads();
    if (abl) break;
  }

  // final f32 state -> d_out
  #pragma unroll
  for (int j = 0; j < 4; j++) {
    int n = r0 + l4 * 4 + j;
    out[(size_t)n * ED + c0 + wc] = ms[j];
  }
}

__global__ void fail_kernel(float* out) {
  if (threadIdx.x == 0 && blockIdx.x == 0) out[0] = -54321.0f;
}

extern "C" void kernel_launch(void* const* d_in, const int* in_sizes, int n_in,
                              void* d_out, int out_size, void* d_ws, size_t ws_size,
                              hipStream_t stream) {
  const int* utt = (const int*)d_in[0];
  const float* emb = (const float*)d_in[1];
  const float* Wih = (const float*)d_in[2];
  const float* Whh = (const float*)d_in[3];
  const float* bih = (const float*)d_in[4];
  const float* bhh = (const float*)d_in[5];
  const int* term = (const int*)d_in[6];
  float* out = (float*)d_out;
  char* ws = (char*)d_ws;

  const size_t tab_b = (size_t)VS * GD * 2;                 // 98,304,000
  const size_t st_b = (size_t)NB * ED * 2;                  // 1,048,576 per buffer
  const size_t off_st = tab_b;
  const size_t off_cnt = off_st + 4 * st_b;
  const size_t need = off_cnt + 16384;

  if (ws_size < need) {  // sentinel: visible failure instead of OOB
    fail_kernel<<<1, 64, 0, stream>>>(out);
    return;
  }

  unsigned short* tab = (unsigned short*)(ws);
  unsigned short* st = (unsigned short*)(ws + off_st);
  unsigned* cnt = (unsigned*)(ws + off_cnt);

  // barriers + abort flag zeroed every launch (L3 domain, deterministic);
  // state buffers are written-before-read within each call (s=0 skips load)
  (void)hipMemsetAsync(cnt, 0, 16384, stream);

  table_kernel<<<dim3(250, 12), 256, 0, stream>>>(emb, Wih, bih, tab);
  gru_kernel<<<256, 512, 0, stream>>>(utt, Whh, bhh, tab, st, cnt, term, out);
}